// Round 2
// baseline (182.632 us; speedup 1.0000x reference)
//
#include <hip/hip_runtime.h>

// ComboSumModule: six independent sum-over-axis-1 reductions (f32).
// Shapes (compile-time): (2048,128,64) (2048,32,32) (2048,64,64)
//                        (2048,16,48) (2048,200,32) (2048,8,8)
// Outputs concatenated flat in return order.
//
// R1 post-mortem: one-thread-per-output capped us at 1984 waves (7.75/CU),
// occupancy 11%, latency-bound at 64us. R2: split the reduce dim M across
// 4 waves per 256-thread block (same 64 float4 outputs per block), LDS
// combine. 1984 blocks x 4 waves = 7936 waves = 31/CU.

__device__ __forceinline__ float4 f4add(float4 a, float4 b) {
  return make_float4(a.x + b.x, a.y + b.y, a.z + b.z, a.w + b.w);
}

template <int M, int N>
__device__ __forceinline__ void col_sum(const float* __restrict__ xp,
                                        float* __restrict__ out,
                                        int local, int wave, int lane,
                                        int out_base4, float4* lds) {
  constexpr int N4 = N / 4;
  constexpr int R = M / 4;  // rows handled by each of the 4 waves
  static_assert(R % 2 == 0, "R divisible by 2");
  const int b  = local / N4;          // const divisor -> magic-mul
  const int n4 = local - b * N4;
  const float4* __restrict__ p =
      reinterpret_cast<const float4*>(xp) + (size_t)b * (M * N4) +
      (size_t)(wave * R) * N4 + n4;

  float4 a0 = make_float4(0.f, 0.f, 0.f, 0.f);
  float4 a1 = make_float4(0.f, 0.f, 0.f, 0.f);
#pragma unroll 2
  for (int m = 0; m < R; m += 2) {
    float4 v0 = p[(size_t)(m + 0) * N4];
    float4 v1 = p[(size_t)(m + 1) * N4];
    a0 = f4add(a0, v0);
    a1 = f4add(a1, v1);
  }
  lds[wave * 64 + lane] = f4add(a0, a1);
  __syncthreads();
  if (wave == 0) {
    float4 r = f4add(f4add(lds[lane], lds[64 + lane]),
                     f4add(lds[128 + lane], lds[192 + lane]));
    reinterpret_cast<float4*>(out)[out_base4 + local] = r;
  }
}

// Region boundaries in float4 units (all multiples of 64 -> every block is
// region-uniform; __syncthreads under the branch is safe):
//   x0 [0,      32768)  M=128 N=64
//   x1 [32768,  49152)  M=32  N=32
//   x2 [49152,  81920)  M=64  N=64
//   x3 [81920, 106496)  M=16  N=48
//   x4 [106496,122880)  M=200 N=32
//   x5 [122880,126976)  M=8   N=8
__global__ __launch_bounds__(256) void ComboSumModule_25314537242674_kernel(
    const float* __restrict__ x0, const float* __restrict__ x1,
    const float* __restrict__ x2, const float* __restrict__ x3,
    const float* __restrict__ x4, const float* __restrict__ x5,
    float* __restrict__ out) {
  __shared__ float4 lds[4 * 64];
  const int lane = threadIdx.x & 63;
  const int wave = threadIdx.x >> 6;
  const int u = blockIdx.x * 64 + lane;  // this lane's output float4 unit
  if (u < 32768) {
    col_sum<128, 64>(x0, out, u, wave, lane, 0, lds);
  } else if (u < 49152) {
    col_sum<32, 32>(x1, out, u - 32768, wave, lane, 32768, lds);
  } else if (u < 81920) {
    col_sum<64, 64>(x2, out, u - 49152, wave, lane, 49152, lds);
  } else if (u < 106496) {
    col_sum<16, 48>(x3, out, u - 81920, wave, lane, 81920, lds);
  } else if (u < 122880) {
    col_sum<200, 32>(x4, out, u - 106496, wave, lane, 106496, lds);
  } else {
    col_sum<8, 8>(x5, out, u - 122880, wave, lane, 122880, lds);
  }
}

extern "C" void kernel_launch(void* const* d_in, const int* in_sizes, int n_in,
                              void* d_out, int out_size, void* d_ws, size_t ws_size,
                              hipStream_t stream) {
  const float* x0 = (const float*)d_in[0];
  const float* x1 = (const float*)d_in[1];
  const float* x2 = (const float*)d_in[2];
  const float* x3 = (const float*)d_in[3];
  const float* x4 = (const float*)d_in[4];
  const float* x5 = (const float*)d_in[5];
  // d_in[6] is the python scalar dim=1; reduction axis is baked in.
  float* out = (float*)d_out;

  // 126,976 float4 output units = 1984 blocks x 64 units; 256 thr = 4 waves
  // per block splitting the reduce dim.
  ComboSumModule_25314537242674_kernel<<<1984, 256, 0, stream>>>(
      x0, x1, x2, x3, x4, x5, out);
}

// Round 3
// 178.007 us; speedup vs baseline: 1.0260x; 1.0260x over previous
//
#include <hip/hip_runtime.h>

// ComboSumModule: six independent sum-over-axis-1 reductions (f32).
// Shapes: (2048,128,64) (2048,32,32) (2048,64,64) (2048,16,48)
//         (2048,200,32) (2048,8,8). Outputs concatenated flat.
//
// R2 post-mortem: occupancy 4x'd but dur identical (64us) -> straggler tail
// from 25x per-wave work spread (2..50 loads) + only 2 loads in flight
// (VGPR=20). R3: uniform tiles. All M divisible by 8 -> tile = 64 output
// float4s x 8 rows = exactly 8 loads/wave (x4: 12-13). Block = 1024 thr =
// 16 waves; waves-per-group by region {16,8,4,2,1}; LDS combine. Heavy x4
// blocks first. 4 accumulators, unrolled -> ~8 loads in flight.

__device__ __forceinline__ float4 f4add(float4 a, float4 b) {
  return make_float4(a.x + b.x, a.y + b.y, a.z + b.z, a.w + b.w);
}

// One wave sums rows [row_start, row_start+row_cnt) of its 64-unit group.
// WPG = waves per group (subgroup of the 16-wave block). Block-uniform.
template <int M, int N, int WPG>
__device__ __forceinline__ void region(const float* __restrict__ xp,
                                       float* __restrict__ out,
                                       int out_base4, int group, int wave,
                                       int lane, int row_start, int row_cnt,
                                       float4* lds) {
  constexpr int N4 = N / 4;
  const int u = group * 64 + lane;      // unit index local to tensor
  const int b = u / N4;                 // const divisor -> magic-mul
  const int n4 = u - b * N4;
  const float4* __restrict__ p =
      reinterpret_cast<const float4*>(xp) + (size_t)b * (M * N4) +
      (size_t)row_start * N4 + n4;

  float4 a0 = make_float4(0.f, 0.f, 0.f, 0.f);
  float4 a1 = make_float4(0.f, 0.f, 0.f, 0.f);
  float4 a2 = make_float4(0.f, 0.f, 0.f, 0.f);
  float4 a3 = make_float4(0.f, 0.f, 0.f, 0.f);
  int i = 0;
#pragma unroll
  for (; i + 4 <= row_cnt; i += 4) {   // row_cnt=8 const-folds -> 8 loads
    float4 v0 = p[(size_t)(i + 0) * N4];
    float4 v1 = p[(size_t)(i + 1) * N4];
    float4 v2 = p[(size_t)(i + 2) * N4];
    float4 v3 = p[(size_t)(i + 3) * N4];
    a0 = f4add(a0, v0);
    a1 = f4add(a1, v1);
    a2 = f4add(a2, v2);
    a3 = f4add(a3, v3);
  }
  for (; i < row_cnt; ++i)             // x4 tail (cnt 13)
    a0 = f4add(a0, p[(size_t)i * N4]);

  float4 r = f4add(f4add(a0, a1), f4add(a2, a3));

  if (WPG == 1) {
    reinterpret_cast<float4*>(out)[out_base4 + group * 64 + lane] = r;
    return;
  }
  lds[wave * 64 + lane] = r;
  __syncthreads();
  if ((wave & (WPG - 1)) == 0) {       // lead wave of subgroup combines
    float4 s = lds[wave * 64 + lane];
#pragma unroll
    for (int j = 1; j < WPG; ++j) s = f4add(s, lds[(wave + j) * 64 + lane]);
    reinterpret_cast<float4*>(out)[out_base4 + group * 64 + lane] = s;
  }
}

// Block order (heaviest first): x4 [0,256) x0 [256,768) x2 [768,1024)
// x1 [1024,1088) x3 [1088,1136) x5 [1136,1140). Branch is block-uniform.
__global__ __launch_bounds__(1024) void ComboSumModule_25314537242674_kernel(
    const float* __restrict__ x0, const float* __restrict__ x1,
    const float* __restrict__ x2, const float* __restrict__ x3,
    const float* __restrict__ x4, const float* __restrict__ x5,
    float* __restrict__ out) {
  __shared__ float4 lds[16 * 64];      // 16 KB
  const int lane = threadIdx.x & 63;
  const int wave = threadIdx.x >> 6;
  const int blk = blockIdx.x;

  if (blk < 256) {
    // x4: M=200 N=32, 1 group/block, 16 waves: 8x13 + 8x12 rows.
    const int cnt = (wave < 8) ? 13 : 12;
    const int start = 12 * wave + ((wave < 8) ? wave : 8);
    region<200, 32, 16>(x4, out, 106496, blk, wave, lane, start, cnt, lds);
  } else if (blk < 768) {
    // x0: M=128 N=64, 1 group/block, wave w rows [8w, 8w+8).
    region<128, 64, 16>(x0, out, 0, blk - 256, wave, lane, 8 * wave, 8, lds);
  } else if (blk < 1024) {
    // x2: M=64 N=64, 2 groups/block, 8 waves each.
    const int g = (blk - 768) * 2 + (wave >> 3);
    region<64, 64, 8>(x2, out, 49152, g, wave, lane, 8 * (wave & 7), 8, lds);
  } else if (blk < 1088) {
    // x1: M=32 N=32, 4 groups/block, 4 waves each.
    const int g = (blk - 1024) * 4 + (wave >> 2);
    region<32, 32, 4>(x1, out, 32768, g, wave, lane, 8 * (wave & 3), 8, lds);
  } else if (blk < 1136) {
    // x3: M=16 N=48, 8 groups/block, 2 waves each.
    const int g = (blk - 1088) * 8 + (wave >> 1);
    region<16, 48, 2>(x3, out, 81920, g, wave, lane, 8 * (wave & 1), 8, lds);
  } else {
    // x5: M=8 N=8, 16 groups/block, 1 wave each, direct store.
    const int g = (blk - 1136) * 16 + wave;
    region<8, 8, 1>(x5, out, 122880, g, wave, lane, 0, 8, lds);
  }
}

extern "C" void kernel_launch(void* const* d_in, const int* in_sizes, int n_in,
                              void* d_out, int out_size, void* d_ws, size_t ws_size,
                              hipStream_t stream) {
  const float* x0 = (const float*)d_in[0];
  const float* x1 = (const float*)d_in[1];
  const float* x2 = (const float*)d_in[2];
  const float* x3 = (const float*)d_in[3];
  const float* x4 = (const float*)d_in[4];
  const float* x5 = (const float*)d_in[5];
  // d_in[6] is the python scalar dim=1; reduction axis baked in.
  float* out = (float*)d_out;

  ComboSumModule_25314537242674_kernel<<<1140, 1024, 0, stream>>>(
      x0, x1, x2, x3, x4, x5, out);
}

// Round 4
// 177.089 us; speedup vs baseline: 1.0313x; 1.0052x over previous
//
#include <hip/hip_runtime.h>

// ComboSumModule: six independent sum-over-axis-1 reductions (f32).
// Shapes: (2048,128,64) (2048,32,32) (2048,64,64) (2048,16,48)
//         (2048,200,32) (2048,8,8). Outputs concatenated flat.
//
// R3 post-mortem: uniform tiles + 56% occupancy only got 64->58us; HBM
// stuck at 1.45 TB/s, VGPR=28 -> ~2 loads in flight per wave. R4: issue
// ALL of a wave's loads up front into a register array (8-13 float4 = 8-13KB
// in flight/wave), reduce in load order so vmcnt drains incrementally.
// Region map / heavy-first order / LDS combine unchanged from R3.

__device__ __forceinline__ float4 f4add(float4 a, float4 b) {
  return make_float4(a.x + b.x, a.y + b.y, a.z + b.z, a.w + b.w);
}

// Per-wave partial: sum CNT rows starting at row_start for this lane's
// output unit. All CNT loads are issued before any add (max MLP).
template <int M, int N, int CNT>
__device__ __forceinline__ float4 partial(const float* __restrict__ xp,
                                          int group, int row_start, int lane) {
  constexpr int N4 = N / 4;
  const int u = group * 64 + lane;   // unit index local to tensor
  const int b = u / N4;              // const divisor -> magic-mul
  const int n4 = u - b * N4;
  const float4* __restrict__ p =
      reinterpret_cast<const float4*>(xp) + (size_t)b * (M * N4) +
      (size_t)row_start * N4 + n4;

  float4 v[CNT];
#pragma unroll
  for (int i = 0; i < CNT; ++i) v[i] = p[(size_t)i * N4];

  float4 r = v[0];                   // consume in load order: vmcnt(CNT-1-i)
#pragma unroll
  for (int i = 1; i < CNT; ++i) r = f4add(r, v[i]);
  return r;
}

// Combine WPG per-wave partials for a 64-unit group via LDS; lead wave
// stores. WPG==1 stores directly. Barrier is reached by all 16 waves of the
// block (call sites keep this wave-uniform).
template <int WPG>
__device__ __forceinline__ void combine(float4 r, float* __restrict__ out,
                                        int out_base4, int group, int wave,
                                        int lane, float4* lds) {
  if (WPG == 1) {
    reinterpret_cast<float4*>(out)[out_base4 + group * 64 + lane] = r;
    return;
  }
  lds[wave * 64 + lane] = r;
  __syncthreads();
  if ((wave & (WPG - 1)) == 0) {
    float4 s = lds[wave * 64 + lane];
#pragma unroll
    for (int j = 1; j < WPG; ++j) s = f4add(s, lds[(wave + j) * 64 + lane]);
    reinterpret_cast<float4*>(out)[out_base4 + group * 64 + lane] = s;
  }
}

// Block order (heaviest first): x4 [0,256) x0 [256,768) x2 [768,1024)
// x1 [1024,1088) x3 [1088,1136) x5 [1136,1140). Region branch is
// block-uniform; only x4's CNT differs per wave (barrier hoisted out).
__global__ __launch_bounds__(1024) void ComboSumModule_25314537242674_kernel(
    const float* __restrict__ x0, const float* __restrict__ x1,
    const float* __restrict__ x2, const float* __restrict__ x3,
    const float* __restrict__ x4, const float* __restrict__ x5,
    float* __restrict__ out) {
  __shared__ float4 lds[16 * 64];  // 16 KB
  const int lane = threadIdx.x & 63;
  const int wave = threadIdx.x >> 6;
  const int blk = blockIdx.x;

  if (blk < 256) {
    // x4: M=200 N=32, 1 group/block; waves 0-7: 13 rows, waves 8-15: 12.
    float4 r;
    if (wave < 8)
      r = partial<200, 32, 13>(x4, blk, 13 * wave, lane);
    else
      r = partial<200, 32, 12>(x4, blk, 104 + 12 * (wave - 8), lane);
    combine<16>(r, out, 106496, blk, wave, lane, lds);
  } else if (blk < 768) {
    // x0: M=128 N=64, 1 group/block, wave w rows [8w, 8w+8).
    float4 r = partial<128, 64, 8>(x0, blk - 256, 8 * wave, lane);
    combine<16>(r, out, 0, blk - 256, wave, lane, lds);
  } else if (blk < 1024) {
    // x2: M=64 N=64, 2 groups/block, 8 waves each.
    const int g = (blk - 768) * 2 + (wave >> 3);
    float4 r = partial<64, 64, 8>(x2, g, 8 * (wave & 7), lane);
    combine<8>(r, out, 49152, g, wave, lane, lds);
  } else if (blk < 1088) {
    // x1: M=32 N=32, 4 groups/block, 4 waves each.
    const int g = (blk - 1024) * 4 + (wave >> 2);
    float4 r = partial<32, 32, 8>(x1, g, 8 * (wave & 3), lane);
    combine<4>(r, out, 32768, g, wave, lane, lds);
  } else if (blk < 1136) {
    // x3: M=16 N=48, 8 groups/block, 2 waves each.
    const int g = (blk - 1088) * 8 + (wave >> 1);
    float4 r = partial<16, 48, 8>(x3, g, 8 * (wave & 1), lane);
    combine<2>(r, out, 81920, g, wave, lane, lds);
  } else {
    // x5: M=8 N=8, 16 groups/block, 1 wave each, direct store.
    const int g = (blk - 1136) * 16 + wave;
    float4 r = partial<8, 8, 8>(x5, g, 0, lane);
    combine<1>(r, out, 122880, g, wave, lane, lds);
  }
}

extern "C" void kernel_launch(void* const* d_in, const int* in_sizes, int n_in,
                              void* d_out, int out_size, void* d_ws, size_t ws_size,
                              hipStream_t stream) {
  const float* x0 = (const float*)d_in[0];
  const float* x1 = (const float*)d_in[1];
  const float* x2 = (const float*)d_in[2];
  const float* x3 = (const float*)d_in[3];
  const float* x4 = (const float*)d_in[4];
  const float* x5 = (const float*)d_in[5];
  // d_in[6] is the python scalar dim=1; reduction axis baked in.
  float* out = (float*)d_out;

  ComboSumModule_25314537242674_kernel<<<1140, 1024, 0, stream>>>(
      x0, x1, x2, x3, x4, x5, out);
}

// Round 5
// 176.637 us; speedup vs baseline: 1.0339x; 1.0026x over previous
//
#include <hip/hip_runtime.h>

// ComboSumModule: six independent sum-over-axis-1 reductions (f32).
// Shapes: (2048,128,64) (2048,32,32) (2048,64,64) (2048,16,48)
//         (2048,200,32) (2048,8,8). Outputs concatenated flat.
//
// R4 post-mortem: consume-in-load-order let the compiler hoist adds between
// loads (VGPR=32 -> only ~2-3 loads in flight); dur stuck at 58us with waves
// resident-but-stalled 98% (VALUBusy 1.6%, occupancy 56%). R5: consume the
// register array in REVERSE load order -- every add depends on the
// last-issued load, so all CNT buffers must stay live and all CNT loads
// issue back-to-back (true MLP = 8-13 x 1KB per wave). Region map, block
// order, LDS combine unchanged from R4.

__device__ __forceinline__ float4 f4add(float4 a, float4 b) {
  return make_float4(a.x + b.x, a.y + b.y, a.z + b.z, a.w + b.w);
}

// Per-wave partial: sum CNT rows starting at row_start for this lane's
// output unit. All CNT loads issued before any add; reverse-order
// consumption pins all CNT float4 buffers live (forces full MLP).
template <int M, int N, int CNT>
__device__ __forceinline__ float4 partial(const float* __restrict__ xp,
                                          int group, int row_start, int lane) {
  constexpr int N4 = N / 4;
  const int u = group * 64 + lane;   // unit index local to tensor
  const int b = u / N4;              // const divisor -> magic-mul
  const int n4 = u - b * N4;
  const float4* __restrict__ p =
      reinterpret_cast<const float4*>(xp) + (size_t)b * (M * N4) +
      (size_t)row_start * N4 + n4;

  float4 v[CNT];
#pragma unroll
  for (int i = 0; i < CNT; ++i) v[i] = p[(size_t)i * N4];

  // Reverse order: first add needs the LAST load -> compiler cannot hoist
  // any add above any load; all CNT buffers stay live.
  float4 r = v[CNT - 1];
#pragma unroll
  for (int i = CNT - 2; i >= 0; --i) r = f4add(r, v[i]);
  return r;
}

// Combine WPG per-wave partials for a 64-unit group via LDS; lead wave
// stores. WPG==1 stores directly. Barrier reached by all 16 waves.
template <int WPG>
__device__ __forceinline__ void combine(float4 r, float* __restrict__ out,
                                        int out_base4, int group, int wave,
                                        int lane, float4* lds) {
  if (WPG == 1) {
    reinterpret_cast<float4*>(out)[out_base4 + group * 64 + lane] = r;
    return;
  }
  lds[wave * 64 + lane] = r;
  __syncthreads();
  if ((wave & (WPG - 1)) == 0) {
    float4 s = lds[wave * 64 + lane];
#pragma unroll
    for (int j = 1; j < WPG; ++j) s = f4add(s, lds[(wave + j) * 64 + lane]);
    reinterpret_cast<float4*>(out)[out_base4 + group * 64 + lane] = s;
  }
}

// Block order (heaviest first): x4 [0,256) x0 [256,768) x2 [768,1024)
// x1 [1024,1088) x3 [1088,1136) x5 [1136,1140). Region branch is
// block-uniform; only x4's CNT differs per wave (barrier outside).
__global__ __launch_bounds__(1024) void ComboSumModule_25314537242674_kernel(
    const float* __restrict__ x0, const float* __restrict__ x1,
    const float* __restrict__ x2, const float* __restrict__ x3,
    const float* __restrict__ x4, const float* __restrict__ x5,
    float* __restrict__ out) {
  __shared__ float4 lds[16 * 64];  // 16 KB
  const int lane = threadIdx.x & 63;
  const int wave = threadIdx.x >> 6;
  const int blk = blockIdx.x;

  if (blk < 256) {
    // x4: M=200 N=32, 1 group/block; waves 0-7: 13 rows, waves 8-15: 12.
    float4 r;
    if (wave < 8)
      r = partial<200, 32, 13>(x4, blk, 13 * wave, lane);
    else
      r = partial<200, 32, 12>(x4, blk, 104 + 12 * (wave - 8), lane);
    combine<16>(r, out, 106496, blk, wave, lane, lds);
  } else if (blk < 768) {
    // x0: M=128 N=64, 1 group/block, wave w rows [8w, 8w+8).
    float4 r = partial<128, 64, 8>(x0, blk - 256, 8 * wave, lane);
    combine<16>(r, out, 0, blk - 256, wave, lane, lds);
  } else if (blk < 1024) {
    // x2: M=64 N=64, 2 groups/block, 8 waves each.
    const int g = (blk - 768) * 2 + (wave >> 3);
    float4 r = partial<64, 64, 8>(x2, g, 8 * (wave & 7), lane);
    combine<8>(r, out, 49152, g, wave, lane, lds);
  } else if (blk < 1088) {
    // x1: M=32 N=32, 4 groups/block, 4 waves each.
    const int g = (blk - 1024) * 4 + (wave >> 2);
    float4 r = partial<32, 32, 8>(x1, g, 8 * (wave & 3), lane);
    combine<4>(r, out, 32768, g, wave, lane, lds);
  } else if (blk < 1136) {
    // x3: M=16 N=48, 8 groups/block, 2 waves each.
    const int g = (blk - 1088) * 8 + (wave >> 1);
    float4 r = partial<16, 48, 8>(x3, g, 8 * (wave & 1), lane);
    combine<2>(r, out, 81920, g, wave, lane, lds);
  } else {
    // x5: M=8 N=8, 16 groups/block, 1 wave each, direct store.
    const int g = (blk - 1136) * 16 + wave;
    float4 r = partial<8, 8, 8>(x5, g, 0, lane);
    combine<1>(r, out, 122880, g, wave, lane, lds);
  }
}

extern "C" void kernel_launch(void* const* d_in, const int* in_sizes, int n_in,
                              void* d_out, int out_size, void* d_ws, size_t ws_size,
                              hipStream_t stream) {
  const float* x0 = (const float*)d_in[0];
  const float* x1 = (const float*)d_in[1];
  const float* x2 = (const float*)d_in[2];
  const float* x3 = (const float*)d_in[3];
  const float* x4 = (const float*)d_in[4];
  const float* x5 = (const float*)d_in[5];
  // d_in[6] is the python scalar dim=1; reduction axis baked in.
  float* out = (float*)d_out;

  ComboSumModule_25314537242674_kernel<<<1140, 1024, 0, stream>>>(
      x0, x1, x2, x3, x4, x5, out);
}